// Round 5
// baseline (480.801 us; speedup 1.0000x reference)
//
#include <hip/hip_runtime.h>

typedef __attribute__((ext_vector_type(8))) short short8;
typedef __attribute__((ext_vector_type(4))) float f32x4;
typedef __attribute__((ext_vector_type(4))) unsigned int uint4v;
typedef unsigned short ushort;
typedef unsigned int uint;

#define B_  4
#define L_  8192
#define D_  512
#define H_  8
#define F_  65      // DK + PD
#define KVS_ 80     // K/V head-major row stride (65 used + 15 pad)
#define EPS_ 1e-5f

// fp32 -> bf16 round-to-nearest-even
__device__ __forceinline__ ushort f2b(float f) {
    uint x = __float_as_uint(f);
    uint r = (x + 0x7FFFu + ((x >> 16) & 1u)) >> 16;
    return (ushort)r;
}
__device__ __forceinline__ float b2f(ushort u) {
    return __uint_as_float(((uint)u) << 16);
}

#define GLD16(gptr, sptr) \
    __builtin_amdgcn_global_load_lds((const __attribute__((address_space(1))) void*)(gptr), \
                                     (__attribute__((address_space(3))) void*)(sptr), 16, 0, 0)

// Packed bf16 operand tile: 128 rows x 32 k = 4096 shorts; element (row,k) at
// ((k>>3)&3)*1024 + row*8 + (k&7). Operand = tiles [outer_n][ks].

// ---------------- K0: cast Wk/Wv to bf16, tile-packed ----------------
__global__ __launch_bounds__(256)
void cast_w(const float* __restrict__ Wk, const float* __restrict__ Wv,
            ushort* __restrict__ Wb)
{
    const int g = blockIdx.x * 256 + threadIdx.x;   // one 16B group each
    const int inner = g & 511;
    const int tileIdx = g >> 9;                     // (z*4+nt)*16 + ks, z in {0,1}
    const int w   = inner >> 7;
    const int row = inner & 127;
    const int ks  = tileIdx & 15;
    const int nt  = (tileIdx >> 4) & 3;
    const int z   = tileIdx >> 6;
    const float* __restrict__ src = (z == 0) ? Wk : Wv;
    const float* s = &src[(size_t)(nt * 128 + row) * D_ + ks * 32 + w * 8];
    const float4 f0 = *(const float4*)s;
    const float4 f1 = *(const float4*)(s + 4);
    short8 v;
    v[0] = (short)f2b(f0.x); v[1] = (short)f2b(f0.y);
    v[2] = (short)f2b(f0.z); v[3] = (short)f2b(f0.w);
    v[4] = (short)f2b(f1.x); v[5] = (short)f2b(f1.y);
    v[6] = (short)f2b(f1.z); v[7] = (short)f2b(f1.w);
    *(short8*)&Wb[(size_t)tileIdx * 4096 + inner * 8] = v;
}

// ---------------- K1: K/V projection GEMM + fused LN/pos epilogue ----------------
// Tile 128(M) x 512(N full): A read exactly once. 512 threads = 8 waves, each
// wave owns 64 rows x 128 cols (2 heads). Double-buffered LDS, one barrier/K-step.
__global__ __launch_bounds__(512, 2)
void proj_mfma(const float* __restrict__ Xk, const float* __restrict__ Xv,
               const ushort* __restrict__ Wb,
               const float* __restrict__ bk, const float* __restrict__ bv,
               const float* __restrict__ pos,
               const float* __restrict__ gK, const float* __restrict__ betaK,
               const float* __restrict__ gV, const float* __restrict__ betaV,
               ushort* __restrict__ Kh, ushort* __restrict__ Vh)
{
    const int x  = blockIdx.x;                       // [0,256)
    const int m0 = ((x & 7) * 32 + (x >> 3)) * 128;  // chunked XCD map (bijective)
    const int z  = blockIdx.y;                       // 0=K, 1=V

    const float* __restrict__ X    = (z == 0) ? Xk : Xv;
    const float* __restrict__ bias = (z == 0) ? bk : bv;

    const int t  = threadIdx.x;
    const int w  = t >> 6, l = t & 63;
    const int wm = (w >> 2) * 64, wn = (w & 3) * 128;
    const int lg = l >> 4, lm = l & 15;

    __shared__ __align__(16) float sAf[2][4096];    // 2 x 16 KB fp32 A (swizzled slots)
    __shared__ __align__(16) short sB[2][16384];    // 2 x 32 KB bf16 B (4 packed tiles)

    f32x4 acc[4][8];
#pragma unroll
    for (int i = 0; i < 4; ++i)
#pragma unroll
        for (int j = 0; j < 8; ++j) acc[i][j] = (f32x4){0.f, 0.f, 0.f, 0.f};

    // A staging: wave w stages rows w*16..w*16+15 (two 8-row chunks).
    // LDS slot s of row r holds global half-chunk s^(r&7) (pre-swizzled source).
    const int lr = l >> 3;
    const int hg = (l & 7) ^ lr;
    const float* ag[2]; int alo[2];
#pragma unroll
    for (int i = 0; i < 2; ++i) {
        const int row = w * 16 + i * 8 + lr;
        ag[i]  = &X[(size_t)(m0 + row) * D_ + hg * 4];
        alo[i] = (w * 2 + i) * 256;
    }

    // B staging: 4 packed n-tiles per K-step, one GLD16 per thread per tile.
    const ushort* bsrc[4];
#pragma unroll
    for (int nt = 0; nt < 4; ++nt)
        bsrc[nt] = Wb + (size_t)((z * 4 + nt) * 16) * 4096 + t * 8;

    int a0o[4], a1o[4], bro[8];
#pragma unroll
    for (int i = 0; i < 4; ++i) {
        const int r = wm + i * 16 + lm;
        a0o[i] = r * 32 + (((lg * 2)     ^ (r & 7)) * 4);
        a1o[i] = r * 32 + (((lg * 2 + 1) ^ (r & 7)) * 4);
    }
#pragma unroll
    for (int i = 0; i < 8; ++i) {
        const int col = wn + i * 16 + lm;            // [0,512)
        bro[i] = (col >> 7) * 4096 + lg * 1024 + (col & 127) * 8;
    }

    auto stage = [&](int ks, int buf) {
#pragma unroll
        for (int i = 0; i < 2; ++i) GLD16(ag[i] + ks * 32, &sAf[buf][alo[i]]);
#pragma unroll
        for (int nt = 0; nt < 4; ++nt)
            GLD16(bsrc[nt] + (size_t)ks * 4096, &sB[buf][nt * 4096 + t * 8]);
    };

    stage(0, 0);
    int cur = 0;
#pragma unroll
    for (int ks = 0; ks < 16; ++ks) {
        __syncthreads();                    // drains stage(ks); buf cur^1 free
        if (ks < 15) stage(ks + 1, cur ^ 1);

        short8 af[4], bfv[8];
#pragma unroll
        for (int i = 0; i < 4; ++i) {
            const f32x4 A0 = *(const f32x4*)&sAf[cur][a0o[i]];
            const f32x4 A1 = *(const f32x4*)&sAf[cur][a1o[i]];
            uint u0, u1, u2, u3;
            asm("v_cvt_pk_bf16_f32 %0, %1, %2" : "=v"(u0) : "v"(A0[0]), "v"(A0[1]));
            asm("v_cvt_pk_bf16_f32 %0, %1, %2" : "=v"(u1) : "v"(A0[2]), "v"(A0[3]));
            asm("v_cvt_pk_bf16_f32 %0, %1, %2" : "=v"(u2) : "v"(A1[0]), "v"(A1[1]));
            asm("v_cvt_pk_bf16_f32 %0, %1, %2" : "=v"(u3) : "v"(A1[2]), "v"(A1[3]));
            union { uint4v u4; short8 s8; } cv;
            cv.u4 = (uint4v){u0, u1, u2, u3};
            af[i] = cv.s8;
        }
#pragma unroll
        for (int i = 0; i < 8; ++i) bfv[i] = *(const short8*)&sB[cur][bro[i]];
#pragma unroll
        for (int mt = 0; mt < 4; ++mt)
#pragma unroll
            for (int nt = 0; nt < 8; ++nt)
                acc[mt][nt] = __builtin_amdgcn_mfma_f32_16x16x32_bf16(
                    af[mt], bfv[nt], acc[mt][nt], 0, 0, 0);

        cur ^= 1;
    }

    // -------- fused LN epilogue (wave: 64 rows x heads h0,h0+1) --------
    const int h0 = wn >> 6;
    float bvv[8];
#pragma unroll
    for (int nt = 0; nt < 8; ++nt) bvv[nt] = bias[wn + nt * 16 + lm];

    const float* gp = (z == 0) ? gK : gV;
    const float* bp = (z == 0) ? betaK : betaV;
    ushort* Oh = (z == 0) ? Kh : Vh;
    float gg[8], bb2[8];
#pragma unroll
    for (int nt = 0; nt < 8; ++nt) {
        const int idx = (h0 + (nt >> 2)) * 64 + (nt & 3) * 16 + lm;
        gg[nt]  = gp[idx];
        bb2[nt] = bp[idx];
    }
#pragma unroll
    for (int mt = 0; mt < 4; ++mt) {
#pragma unroll
        for (int r = 0; r < 4; ++r) {
            const int m = m0 + wm + mt * 16 + lg * 4 + r;
            const int bb = m >> 13, ll = m & 8191;
#pragma unroll
            for (int g = 0; g < 2; ++g) {
                const float v0 = acc[mt][g * 4 + 0][r] + bvv[g * 4 + 0];
                const float v1 = acc[mt][g * 4 + 1][r] + bvv[g * 4 + 1];
                const float v2 = acc[mt][g * 4 + 2][r] + bvv[g * 4 + 2];
                const float v3 = acc[mt][g * 4 + 3][r] + bvv[g * 4 + 3];
                float s = v0 + v1 + v2 + v3;
                float q = v0 * v0 + v1 * v1 + v2 * v2 + v3 * v3;
                s += __shfl_xor(s, 1); s += __shfl_xor(s, 2);
                s += __shfl_xor(s, 4); s += __shfl_xor(s, 8);
                q += __shfl_xor(q, 1); q += __shfl_xor(q, 2);
                q += __shfl_xor(q, 4); q += __shfl_xor(q, 8);
                const float mean = s * (1.f / 64.f);
                const float var = q * (1.f / 64.f) - mean * mean;
                const float rs = rsqrtf(var + EPS_);
                const int h = h0 + g;
                ushort* row = Oh + ((size_t)(bb * H_ + h) * L_ + ll) * KVS_;
                row[1 + 0 * 16 + lm] = f2b((v0 - mean) * rs * gg[g * 4 + 0] + bb2[g * 4 + 0]);
                row[1 + 1 * 16 + lm] = f2b((v1 - mean) * rs * gg[g * 4 + 1] + bb2[g * 4 + 1]);
                row[1 + 2 * 16 + lm] = f2b((v2 - mean) * rs * gg[g * 4 + 2] + bb2[g * 4 + 2]);
                row[1 + 3 * 16 + lm] = f2b((v3 - mean) * rs * gg[g * 4 + 3] + bb2[g * 4 + 3]);
                if (lm == 15) row[0] = f2b(pos[m]);
                else          row[F_ + lm] = 0;   // pad cols 65..79
            }
        }
    }
}

// ---------------- K3: attn accumulation: sum_l K[l][d]*V[l][e] ----------------
__global__ __launch_bounds__(256)
void attn_accum(const ushort* __restrict__ Kh, const ushort* __restrict__ Vh,
                float* __restrict__ attn_acc)
{
    const int s = blockIdx.x;
    const int h = blockIdx.y;
    const int b = blockIdx.z;
    const int t = threadIdx.x;

    __shared__ __align__(16) float Ks[64][84];
    __shared__ __align__(16) float Vs[64][84];

    const size_t base = ((size_t)(b * H_ + h) * L_ + s * 512) * KVS_;

    float acc[5][5];
#pragma unroll
    for (int i = 0; i < 5; ++i)
#pragma unroll
        for (int j = 0; j < 5; ++j) acc[i][j] = 0.f;

    const int dg = t / 13, eg = t % 13;
    const bool act = (t < 169);
    const int d0 = dg * 5, e0 = eg * 5;

    for (int c = 0; c < 8; ++c) {
#pragma unroll
        for (int i = 0; i < 3; ++i) {
            const int slot = t + i * 256;
            if (slot < 640) {
                const int r = slot / 10;
                const int cc = (slot - r * 10) * 8;
                const size_t g = base + (size_t)(c * 64 + r) * KVS_ + cc;
                const short8 kv = *(const short8*)(const void*)&Kh[g];
                const short8 vv = *(const short8*)(const void*)&Vh[g];
                float* kd = &Ks[r][cc];
                float* vd = &Vs[r][cc];
#pragma unroll
                for (int e = 0; e < 8; ++e) {
                    kd[e] = b2f((ushort)kv[e]);
                    vd[e] = b2f((ushort)vv[e]);
                }
            }
        }
        __syncthreads();
        if (act) {
#pragma unroll 2
            for (int l = 0; l < 64; ++l) {
                float kf[5], vf[5];
#pragma unroll
                for (int i = 0; i < 5; ++i) kf[i] = Ks[l][d0 + i];
#pragma unroll
                for (int j = 0; j < 5; ++j) vf[j] = Vs[l][e0 + j];
#pragma unroll
                for (int i = 0; i < 5; ++i)
#pragma unroll
                    for (int j = 0; j < 5; ++j)
                        acc[i][j] = fmaf(kf[i], vf[j], acc[i][j]);
            }
        }
        __syncthreads();
    }

    if (act) {
        float* dst = attn_acc + (size_t)(b * H_ + h) * (F_ * F_);
#pragma unroll
        for (int i = 0; i < 5; ++i)
#pragma unroll
            for (int j = 0; j < 5; ++j)
                atomicAdd(&dst[(d0 + i) * F_ + (e0 + j)], acc[i][j]);
    }
}

// ---------------- K4: attn/L -> attn_out; Gq (fp32), gt0 (fp32) ----------------
// Gq[b][n][d], d = h*64 + (col-1) for col>=1; gt0[b][n][h] = G[n, h*F+0].
__global__ __launch_bounds__(256)
void attn_fin(const float* __restrict__ attn_acc, const float* __restrict__ fcW,
              float* __restrict__ attn_out, float* __restrict__ Gq,
              float* __restrict__ gt0)
{
    const int nc = blockIdx.x;
    const int h = blockIdx.y;
    const int b = blockIdx.z;
    const int t = threadIdx.x;

    __shared__ float S[F_][F_];
    __shared__ float Wl[64][F_];

    const float inv = 1.0f / (float)L_;
    const float* __restrict__ src = attn_acc + (size_t)(b * H_ + h) * F_ * F_;
    for (int idx = t; idx < F_ * F_; idx += 256) {
        const float v = src[idx] * inv;
        S[idx / F_][idx % F_] = v;
        if (nc == 0) attn_out[(size_t)(b * H_ + h) * F_ * F_ + idx] = v;
    }
    for (int idx = t; idx < 64 * F_; idx += 256) {
        const int j = idx / F_;
        const int e = idx - j * F_;
        Wl[j][e] = fcW[(size_t)(nc * 64 + j) * (H_ * F_) + h * F_ + e];
    }
    __syncthreads();

    for (int idx = t; idx < F_ * 64; idx += 256) {
        const int d = idx >> 6;
        const int j = idx & 63;
        float g = 0.f;
#pragma unroll 5
        for (int e = 0; e < F_; ++e) g = fmaf(S[d][e], Wl[j][e], g);
        const int n = nc * 64 + j;
        if (d == 0) gt0[((size_t)b * 512 + n) * 8 + h] = g;
        else        Gq[((size_t)b * 512 + n) * 512 + h * 64 + (d - 1)] = g;
    }
}

// ---------------- K4b: W2[b][n][k] = sum_d Gq[b][n][d]*Wq[d][k] (packed bf16);
//                  P[b][n] = sum_h gt0; C2[b][n] = fcb[n] + sum_d bq[d]*Gq ------
__global__ __launch_bounds__(256)
void w2_build(const float* __restrict__ Gq, const float* __restrict__ gt0,
              const float* __restrict__ Wq, const float* __restrict__ bq,
              const float* __restrict__ fcb, ushort* __restrict__ W2pk,
              float* __restrict__ Pv, float* __restrict__ C2v)
{
    const int kt  = blockIdx.x;   // k-tile 0..7
    const int ntb = blockIdx.y;   // n-tile 0..7
    const int b   = blockIdx.z;
    const int t   = threadIdx.x;
    const int n0 = ntb * 64, k0 = kt * 64;

    __shared__ float Sg[64][65];
    __shared__ float Sw[64][65];

    const float* __restrict__ gq = Gq + (size_t)b * 262144;

    float acc[4][4];
#pragma unroll
    for (int i = 0; i < 4; ++i)
#pragma unroll
        for (int j = 0; j < 4; ++j) acc[i][j] = 0.f;
    float c2a[4] = {0.f, 0.f, 0.f, 0.f};

    const int tn = t >> 4, tk = t & 15;

    for (int dc = 0; dc < 8; ++dc) {
        const int d0 = dc * 64;
        for (int idx = t; idx < 4096; idx += 256) {
            const int rr = idx >> 6, cc = idx & 63;
            Sg[rr][cc] = gq[(size_t)(n0 + rr) * 512 + d0 + cc];
            Sw[rr][cc] = Wq[(size_t)(d0 + rr) * 512 + k0 + cc];
        }
        __syncthreads();
        for (int dd = 0; dd < 64; ++dd) {
            float gf[4], wf[4];
#pragma unroll
            for (int i = 0; i < 4; ++i) gf[i] = Sg[tn * 4 + i][dd];
#pragma unroll
            for (int j = 0; j < 4; ++j) wf[j] = Sw[dd][tk * 4 + j];
#pragma unroll
            for (int i = 0; i < 4; ++i)
#pragma unroll
                for (int j = 0; j < 4; ++j)
                    acc[i][j] = fmaf(gf[i], wf[j], acc[i][j]);
        }
        if (tk == 0) {
            for (int dd = 0; dd < 64; ++dd) {
                const float bqv = bq[d0 + dd];
#pragma unroll
                for (int i = 0; i < 4; ++i)
                    c2a[i] = fmaf(bqv, Sg[tn * 4 + i][dd], c2a[i]);
            }
        }
        __syncthreads();
    }

    ushort* wp = W2pk + (size_t)b * 262144;
#pragma unroll
    for (int i = 0; i < 4; ++i)
#pragma unroll
        for (int j = 0; j < 4; ++j) {
            const int n = n0 + tn * 4 + i;
            const int k = k0 + tk * 4 + j;
            wp[(size_t)((n >> 7) * 16 + (k >> 5)) * 4096 +
               ((k >> 3) & 3) * 1024 + (n & 127) * 8 + (k & 7)] = f2b(acc[i][j]);
        }
    if (kt == 0 && tk == 0) {
#pragma unroll
        for (int i = 0; i < 4; ++i) {
            const int n = n0 + tn * 4 + i;
            float p = 0.f;
#pragma unroll
            for (int h = 0; h < 8; ++h) p += gt0[((size_t)b * 512 + n) * 8 + h];
            Pv[b * 512 + n]  = p;
            C2v[b * 512 + n] = fcb[n] + c2a[i];
        }
    }
}

// ---------------- K5: out = query @ W2^T-ish + pos*P + C2 (128x512 tile) ------
__global__ __launch_bounds__(512, 2)
void out_mfma(const float* __restrict__ query, const ushort* __restrict__ W2pk,
              const float* __restrict__ pos, const float* __restrict__ Pv,
              const float* __restrict__ C2v, float* __restrict__ out)
{
    const int x  = blockIdx.x;                       // [0,256)
    const int m0 = ((x & 7) * 32 + (x >> 3)) * 128;  // chunked XCD map
    const int b  = m0 >> 13;
    const int t  = threadIdx.x;
    const int w  = t >> 6, l = t & 63;
    const int wm = (w >> 2) * 64, wn = (w & 3) * 128;
    const int lg = l >> 4, lm = l & 15;

    __shared__ __align__(16) float sAf[2][4096];
    __shared__ __align__(16) short sB[2][16384];

    f32x4 acc[4][8];
#pragma unroll
    for (int i = 0; i < 4; ++i)
#pragma unroll
        for (int j = 0; j < 8; ++j) acc[i][j] = (f32x4){0.f, 0.f, 0.f, 0.f};

    const int lr = l >> 3;
    const int hg = (l & 7) ^ lr;
    const float* ag[2]; int alo[2];
#pragma unroll
    for (int i = 0; i < 2; ++i) {
        const int row = w * 16 + i * 8 + lr;
        ag[i]  = &query[(size_t)(m0 + row) * D_ + hg * 4];
        alo[i] = (w * 2 + i) * 256;
    }

    const ushort* bsrc[4];
#pragma unroll
    for (int nt = 0; nt < 4; ++nt)
        bsrc[nt] = W2pk + (size_t)b * 262144 + (size_t)(nt * 16) * 4096 + t * 8;

    int a0o[4], a1o[4], bro[8];
#pragma unroll
    for (int i = 0; i < 4; ++i) {
        const int r = wm + i * 16 + lm;
        a0o[i] = r * 32 + (((lg * 2)     ^ (r & 7)) * 4);
        a1o[i] = r * 32 + (((lg * 2 + 1) ^ (r & 7)) * 4);
    }
#pragma unroll
    for (int i = 0; i < 8; ++i) {
        const int col = wn + i * 16 + lm;
        bro[i] = (col >> 7) * 4096 + lg * 1024 + (col & 127) * 8;
    }

    auto stage = [&](int ks, int buf) {
#pragma unroll
        for (int i = 0; i < 2; ++i) GLD16(ag[i] + ks * 32, &sAf[buf][alo[i]]);
#pragma unroll
        for (int nt = 0; nt < 4; ++nt)
            GLD16(bsrc[nt] + (size_t)ks * 4096, &sB[buf][nt * 4096 + t * 8]);
    };

    stage(0, 0);
    int cur = 0;
#pragma unroll
    for (int ks = 0; ks < 16; ++ks) {
        __syncthreads();
        if (ks < 15) stage(ks + 1, cur ^ 1);

        short8 af[4], bfv[8];
#pragma unroll
        for (int i = 0; i < 4; ++i) {
            const f32x4 A0 = *(const f32x4*)&sAf[cur][a0o[i]];
            const f32x4 A1 = *(const f32x4*)&sAf[cur][a1o[i]];
            uint u0, u1, u2, u3;
            asm("v_cvt_pk_bf16_f32 %0, %1, %2" : "=v"(u0) : "v"(A0[0]), "v"(A0[1]));
            asm("v_cvt_pk_bf16_f32 %0, %1, %2" : "=v"(u1) : "v"(A0[2]), "v"(A0[3]));
            asm("v_cvt_pk_bf16_f32 %0, %1, %2" : "=v"(u2) : "v"(A1[0]), "v"(A1[1]));
            asm("v_cvt_pk_bf16_f32 %0, %1, %2" : "=v"(u3) : "v"(A1[2]), "v"(A1[3]));
            union { uint4v u4; short8 s8; } cv;
            cv.u4 = (uint4v){u0, u1, u2, u3};
            af[i] = cv.s8;
        }
#pragma unroll
        for (int i = 0; i < 8; ++i) bfv[i] = *(const short8*)&sB[cur][bro[i]];
#pragma unroll
        for (int mt = 0; mt < 4; ++mt)
#pragma unroll
            for (int nt = 0; nt < 8; ++nt)
                acc[mt][nt] = __builtin_amdgcn_mfma_f32_16x16x32_bf16(
                    af[mt], bfv[nt], acc[mt][nt], 0, 0, 0);

        cur ^= 1;
    }

    float pv[8], c2[8];
#pragma unroll
    for (int nt = 0; nt < 8; ++nt) {
        const int n = wn + nt * 16 + lm;
        pv[nt] = Pv[b * 512 + n];
        c2[nt] = C2v[b * 512 + n];
    }

#pragma unroll
    for (int mt = 0; mt < 4; ++mt) {
#pragma unroll
        for (int r = 0; r < 4; ++r) {
            const int row = m0 + wm + mt * 16 + lg * 4 + r;
            const float pr = pos[row];
            float* orow = out + (size_t)row * D_;
#pragma unroll
            for (int nt = 0; nt < 8; ++nt)
                orow[wn + nt * 16 + lm] = acc[mt][nt][r] + pr * pv[nt] + c2[nt];
        }
    }
}

extern "C" void kernel_launch(void* const* d_in, const int* in_sizes, int n_in,
                              void* d_out, int out_size, void* d_ws, size_t ws_size,
                              hipStream_t stream)
{
    const float* query = (const float*)d_in[0];
    const float* key   = (const float*)d_in[1];
    const float* value = (const float*)d_in[2];
    const float* pos   = (const float*)d_in[3];
    const float* Wq    = (const float*)d_in[4];
    const float* bq    = (const float*)d_in[5];
    const float* Wk    = (const float*)d_in[6];
    const float* bk    = (const float*)d_in[7];
    const float* Wv    = (const float*)d_in[8];
    const float* bv    = (const float*)d_in[9];
    const float* gK    = (const float*)d_in[10];
    const float* betaK = (const float*)d_in[11];
    const float* gV    = (const float*)d_in[12];
    const float* betaV = (const float*)d_in[13];
    const float* fcW   = (const float*)d_in[14];
    const float* fcb   = (const float*)d_in[15];

    char* ws = (char*)d_ws;
    ushort* Kh       = (ushort*)(ws + 0);            // [4][8][8192][80] bf16
    ushort* Vh       = (ushort*)(ws + 41943040);     // [4][8][8192][80] bf16
    ushort* Wb       = (ushort*)(ws + 83886080);     // 2x4x16 packed tiles (1 MB)
    float*  attn_acc = (float*) (ws + 84934656);     // [4][8][65][65] fp32
    float*  Gq       = (float*) (ws + 85479424);     // [4][512][512] fp32
    float*  gt0      = (float*) (ws + 89673728);     // [4][512][8] fp32
    ushort* W2pk     = (ushort*)(ws + 89739264);     // [4][64] packed tiles (2 MB)
    float*  Pv       = (float*) (ws + 91836416);     // [4][512]
    float*  C2v      = (float*) (ws + 91844608);     // [4][512]

    float* att_out  = (float*)d_out;                 // [4][8192][512]
    float* attn_out = att_out + 16777216;            // [4][8][65][65]

    hipMemsetAsync(attn_acc, 0, (size_t)135200 * sizeof(float), stream);

    cast_w<<<dim3(256), 256, 0, stream>>>(Wk, Wv, Wb);

    proj_mfma<<<dim3(256, 2), 512, 0, stream>>>(
        key, value, Wb, bk, bv, pos, gK, betaK, gV, betaV, Kh, Vh);

    attn_accum<<<dim3(16, 8, 4), 256, 0, stream>>>(Kh, Vh, attn_acc);

    attn_fin<<<dim3(8, 8, 4), 256, 0, stream>>>(attn_acc, fcW, attn_out, Gq, gt0);

    w2_build<<<dim3(8, 8, 4), 256, 0, stream>>>(Gq, gt0, Wq, bq, fcb, W2pk, Pv, C2v);

    out_mfma<<<dim3(256), 512, 0, stream>>>(query, W2pk, pos, Pv, C2v, att_out);
}

// Round 6
// 411.179 us; speedup vs baseline: 1.1693x; 1.1693x over previous
//
#include <hip/hip_runtime.h>

typedef __attribute__((ext_vector_type(8))) short short8;
typedef __attribute__((ext_vector_type(4))) float f32x4;
typedef __attribute__((ext_vector_type(4))) unsigned int uint4v;
typedef unsigned short ushort;
typedef unsigned int uint;

#define B_  4
#define L_  8192
#define D_  512
#define H_  8
#define F_  65      // DK + PD
#define KVS_ 80     // K/V head-major row stride (65 used + 15 pad)
#define EPS_ 1e-5f

// fp32 -> bf16 round-to-nearest-even
__device__ __forceinline__ ushort f2b(float f) {
    uint x = __float_as_uint(f);
    uint r = (x + 0x7FFFu + ((x >> 16) & 1u)) >> 16;
    return (ushort)r;
}
__device__ __forceinline__ float b2f(ushort u) {
    return __uint_as_float(((uint)u) << 16);
}

#define GLD16(gptr, sptr) \
    __builtin_amdgcn_global_load_lds((const __attribute__((address_space(1))) void*)(gptr), \
                                     (__attribute__((address_space(3))) void*)(sptr), 16, 0, 0)

// ---------------- K0: cast Wk/Wv to bf16, tile-packed ----------------
__global__ __launch_bounds__(256)
void cast_w(const float* __restrict__ Wk, const float* __restrict__ Wv,
            ushort* __restrict__ Wb)
{
    const int g = blockIdx.x * 256 + threadIdx.x;
    const int inner = g & 511;
    const int tileIdx = g >> 9;
    const int w   = inner >> 7;
    const int row = inner & 127;
    const int ks  = tileIdx & 15;
    const int nt  = (tileIdx >> 4) & 3;
    const int z   = tileIdx >> 6;
    const float* __restrict__ src = (z == 0) ? Wk : Wv;
    const float* s = &src[(size_t)(nt * 128 + row) * D_ + ks * 32 + w * 8];
    const float4 f0 = *(const float4*)s;
    const float4 f1 = *(const float4*)(s + 4);
    short8 v;
    v[0] = (short)f2b(f0.x); v[1] = (short)f2b(f0.y);
    v[2] = (short)f2b(f0.z); v[3] = (short)f2b(f0.w);
    v[4] = (short)f2b(f1.x); v[5] = (short)f2b(f1.y);
    v[6] = (short)f2b(f1.z); v[7] = (short)f2b(f1.w);
    *(short8*)&Wb[(size_t)tileIdx * 4096 + inner * 8] = v;
}

// ---------------- K1: K/V projection GEMM + fused LN/pos epilogue ----------------
__global__ __launch_bounds__(512, 2)
void proj_mfma(const float* __restrict__ Xk, const float* __restrict__ Xv,
               const ushort* __restrict__ Wb,
               const float* __restrict__ bk, const float* __restrict__ bv,
               const float* __restrict__ pos,
               const float* __restrict__ gK, const float* __restrict__ betaK,
               const float* __restrict__ gV, const float* __restrict__ betaV,
               ushort* __restrict__ Kh, ushort* __restrict__ Vh)
{
    const int x  = blockIdx.x;
    const int m0 = ((x & 7) * 32 + (x >> 3)) * 128;
    const int z  = blockIdx.y;

    const float* __restrict__ X    = (z == 0) ? Xk : Xv;
    const float* __restrict__ bias = (z == 0) ? bk : bv;

    const int t  = threadIdx.x;
    const int w  = t >> 6, l = t & 63;
    const int wm = (w >> 2) * 64, wn = (w & 3) * 128;
    const int lg = l >> 4, lm = l & 15;

    __shared__ __align__(16) float sAf[2][4096];
    __shared__ __align__(16) short sB[2][16384];

    f32x4 acc[4][8];
#pragma unroll
    for (int i = 0; i < 4; ++i)
#pragma unroll
        for (int j = 0; j < 8; ++j) acc[i][j] = (f32x4){0.f, 0.f, 0.f, 0.f};

    const int lr = l >> 3;
    const int hg = (l & 7) ^ lr;
    const float* ag[2]; int alo[2];
#pragma unroll
    for (int i = 0; i < 2; ++i) {
        const int row = w * 16 + i * 8 + lr;
        ag[i]  = &X[(size_t)(m0 + row) * D_ + hg * 4];
        alo[i] = (w * 2 + i) * 256;
    }

    const ushort* bsrc[4];
#pragma unroll
    for (int nt = 0; nt < 4; ++nt)
        bsrc[nt] = Wb + (size_t)((z * 4 + nt) * 16) * 4096 + t * 8;

    int a0o[4], a1o[4], bro[8];
#pragma unroll
    for (int i = 0; i < 4; ++i) {
        const int r = wm + i * 16 + lm;
        a0o[i] = r * 32 + (((lg * 2)     ^ (r & 7)) * 4);
        a1o[i] = r * 32 + (((lg * 2 + 1) ^ (r & 7)) * 4);
    }
#pragma unroll
    for (int i = 0; i < 8; ++i) {
        const int col = wn + i * 16 + lm;
        bro[i] = (col >> 7) * 4096 + lg * 1024 + (col & 127) * 8;
    }

    auto stage = [&](int ks, int buf) {
#pragma unroll
        for (int i = 0; i < 2; ++i) GLD16(ag[i] + ks * 32, &sAf[buf][alo[i]]);
#pragma unroll
        for (int nt = 0; nt < 4; ++nt)
            GLD16(bsrc[nt] + (size_t)ks * 4096, &sB[buf][nt * 4096 + t * 8]);
    };

    stage(0, 0);
    int cur = 0;
#pragma unroll
    for (int ks = 0; ks < 16; ++ks) {
        __syncthreads();
        if (ks < 15) stage(ks + 1, cur ^ 1);

        short8 af[4], bfv[8];
#pragma unroll
        for (int i = 0; i < 4; ++i) {
            const f32x4 A0 = *(const f32x4*)&sAf[cur][a0o[i]];
            const f32x4 A1 = *(const f32x4*)&sAf[cur][a1o[i]];
            uint u0, u1, u2, u3;
            asm("v_cvt_pk_bf16_f32 %0, %1, %2" : "=v"(u0) : "v"(A0[0]), "v"(A0[1]));
            asm("v_cvt_pk_bf16_f32 %0, %1, %2" : "=v"(u1) : "v"(A0[2]), "v"(A0[3]));
            asm("v_cvt_pk_bf16_f32 %0, %1, %2" : "=v"(u2) : "v"(A1[0]), "v"(A1[1]));
            asm("v_cvt_pk_bf16_f32 %0, %1, %2" : "=v"(u3) : "v"(A1[2]), "v"(A1[3]));
            union { uint4v u4; short8 s8; } cv;
            cv.u4 = (uint4v){u0, u1, u2, u3};
            af[i] = cv.s8;
        }
#pragma unroll
        for (int i = 0; i < 8; ++i) bfv[i] = *(const short8*)&sB[cur][bro[i]];
#pragma unroll
        for (int mt = 0; mt < 4; ++mt)
#pragma unroll
            for (int nt = 0; nt < 8; ++nt)
                acc[mt][nt] = __builtin_amdgcn_mfma_f32_16x16x32_bf16(
                    af[mt], bfv[nt], acc[mt][nt], 0, 0, 0);

        cur ^= 1;
    }

    const int h0 = wn >> 6;
    float bvv[8];
#pragma unroll
    for (int nt = 0; nt < 8; ++nt) bvv[nt] = bias[wn + nt * 16 + lm];

    const float* gp = (z == 0) ? gK : gV;
    const float* bp = (z == 0) ? betaK : betaV;
    ushort* Oh = (z == 0) ? Kh : Vh;
    float gg[8], bb2[8];
#pragma unroll
    for (int nt = 0; nt < 8; ++nt) {
        const int idx = (h0 + (nt >> 2)) * 64 + (nt & 3) * 16 + lm;
        gg[nt]  = gp[idx];
        bb2[nt] = bp[idx];
    }
#pragma unroll
    for (int mt = 0; mt < 4; ++mt) {
#pragma unroll
        for (int r = 0; r < 4; ++r) {
            const int m = m0 + wm + mt * 16 + lg * 4 + r;
            const int bb = m >> 13, ll = m & 8191;
#pragma unroll
            for (int g = 0; g < 2; ++g) {
                const float v0 = acc[mt][g * 4 + 0][r] + bvv[g * 4 + 0];
                const float v1 = acc[mt][g * 4 + 1][r] + bvv[g * 4 + 1];
                const float v2 = acc[mt][g * 4 + 2][r] + bvv[g * 4 + 2];
                const float v3 = acc[mt][g * 4 + 3][r] + bvv[g * 4 + 3];
                float s = v0 + v1 + v2 + v3;
                float q = v0 * v0 + v1 * v1 + v2 * v2 + v3 * v3;
                s += __shfl_xor(s, 1); s += __shfl_xor(s, 2);
                s += __shfl_xor(s, 4); s += __shfl_xor(s, 8);
                q += __shfl_xor(q, 1); q += __shfl_xor(q, 2);
                q += __shfl_xor(q, 4); q += __shfl_xor(q, 8);
                const float mean = s * (1.f / 64.f);
                const float var = q * (1.f / 64.f) - mean * mean;
                const float rs = rsqrtf(var + EPS_);
                const int h = h0 + g;
                ushort* row = Oh + ((size_t)(bb * H_ + h) * L_ + ll) * KVS_;
                row[1 + 0 * 16 + lm] = f2b((v0 - mean) * rs * gg[g * 4 + 0] + bb2[g * 4 + 0]);
                row[1 + 1 * 16 + lm] = f2b((v1 - mean) * rs * gg[g * 4 + 1] + bb2[g * 4 + 1]);
                row[1 + 2 * 16 + lm] = f2b((v2 - mean) * rs * gg[g * 4 + 2] + bb2[g * 4 + 2]);
                row[1 + 3 * 16 + lm] = f2b((v3 - mean) * rs * gg[g * 4 + 3] + bb2[g * 4 + 3]);
                if (lm == 15) row[0] = f2b(pos[m]);
                else          row[F_ + lm] = 0;
            }
        }
    }
}

// ---------------- K3: attn accumulation via MFMA ----------------
// attn[d][e] = sum_l K[l][d]*V[l][e]: stage K^T,V^T (bf16) in LDS with
// XOR-swizzled l-blocks; A-frag row=d/k=l and B-frag col=e/k=l are contiguous
// b128 reads. Each wave writes its 80x80 partial to a private global slot.
__global__ __launch_bounds__(256, 2)
void attn_accum(const ushort* __restrict__ Kh, const ushort* __restrict__ Vh,
                float* __restrict__ partial)
{
    const int s = blockIdx.x;            // 1024-l slice, 0..7
    const int h = blockIdx.y;
    const int b = blockIdx.z;
    const int bh = b * H_ + h;
    const int t = threadIdx.x;
    const int w = t >> 6, l = t & 63;
    const int lg = l >> 4, lm = l & 15;

    // [80][136] shorts each; element (d,l) at d*136 + (l ^ (((d>>3)&7)<<3))
    __shared__ __align__(16) short stg[21760];
    short* KT = stg;
    short* VT = stg + 10880;

    const size_t base = ((size_t)bh * L_ + (size_t)s * 1024) * KVS_;

    f32x4 acc[5][5];
#pragma unroll
    for (int i = 0; i < 5; ++i)
#pragma unroll
        for (int j = 0; j < 5; ++j) acc[i][j] = (f32x4){0.f, 0.f, 0.f, 0.f};

    for (int c = 0; c < 8; ++c) {
        __syncthreads();                 // previous chunk's readers done
#pragma unroll
        for (int i = 0; i < 5; ++i) {
            const int g  = t + i * 256;  // 0..1279: (l-row, d-group)
            const int lr = g / 10;
            const int dg = g - lr * 10;
            const size_t off = base + (size_t)(c * 128 + lr) * KVS_ + dg * 8;
            const short8 kv = *(const short8*)(const void*)&Kh[off];
            const short8 vv = *(const short8*)(const void*)&Vh[off];
            const int lsw = lr ^ ((dg & 7) << 3);
#pragma unroll
            for (int j = 0; j < 8; ++j) {
                KT[(dg * 8 + j) * 136 + lsw] = kv[j];
                VT[(dg * 8 + j) * 136 + lsw] = vv[j];
            }
        }
        __syncthreads();

        const int l0 = w * 32 + lg * 8;  // wave w owns l-sub [w*32, w*32+32)
        short8 Af[5], Bf[5];
#pragma unroll
        for (int i = 0; i < 5; ++i) {
            const int dr = i * 16 + lm;
            const int sw = ((dr >> 3) & 7) << 3;
            Af[i] = *(const short8*)&KT[dr * 136 + (l0 ^ sw)];
            Bf[i] = *(const short8*)&VT[dr * 136 + (l0 ^ sw)];
        }
#pragma unroll
        for (int i = 0; i < 5; ++i)
#pragma unroll
            for (int j = 0; j < 5; ++j)
                acc[i][j] = __builtin_amdgcn_mfma_f32_16x16x32_bf16(
                    Af[i], Bf[j], acc[i][j], 0, 0, 0);
    }

    // per-wave private partial slot: [s*4+w][bh][80*80]
    float* dst = partial + ((size_t)(s * 4 + w) * 32 + bh) * 6400;
#pragma unroll
    for (int i = 0; i < 5; ++i)
#pragma unroll
        for (int j = 0; j < 5; ++j)
#pragma unroll
            for (int r = 0; r < 4; ++r) {
                const int d = i * 16 + lg * 4 + r;
                const int e = j * 16 + lm;
                dst[d * 80 + e] = acc[i][j][r];
            }
}

// ---------------- K3b: attn_acc[bh][80*80] = sum over 32 partial slots -------
__global__ __launch_bounds__(256)
void acc_reduce(const float* __restrict__ partial, float* __restrict__ attn_acc)
{
    const int bh = blockIdx.y;
    const int q  = blockIdx.x;           // 0..3
    const float4* __restrict__ p4 = (const float4*)partial;
    float4* __restrict__ o4 = (float4*)attn_acc;
    for (int i4 = q * 400 + threadIdx.x; i4 < q * 400 + 400; i4 += 256) {
        float4 s = {0.f, 0.f, 0.f, 0.f};
#pragma unroll
        for (int k = 0; k < 32; ++k) {
            const float4 v = p4[((size_t)k * 32 + bh) * 1600 + i4];
            s.x += v.x; s.y += v.y; s.z += v.z; s.w += v.w;
        }
        o4[(size_t)bh * 1600 + i4] = s;
    }
}

// ---------------- K4: attn/L -> attn_out; Gq (fp32), gt0 (fp32) ----------------
__global__ __launch_bounds__(256)
void attn_fin(const float* __restrict__ attn_acc, const float* __restrict__ fcW,
              float* __restrict__ attn_out, float* __restrict__ Gq,
              float* __restrict__ gt0)
{
    const int nc = blockIdx.x;
    const int h = blockIdx.y;
    const int b = blockIdx.z;
    const int t = threadIdx.x;

    __shared__ float S[F_][F_];
    __shared__ float Wl[64][F_];

    const float inv = 1.0f / (float)L_;
    const float* __restrict__ src = attn_acc + (size_t)(b * H_ + h) * 6400;
    for (int idx = t; idx < F_ * F_; idx += 256) {
        const int d = idx / F_, e = idx - d * F_;
        const float v = src[d * 80 + e] * inv;
        S[d][e] = v;
        if (nc == 0) attn_out[(size_t)(b * H_ + h) * F_ * F_ + idx] = v;
    }
    for (int idx = t; idx < 64 * F_; idx += 256) {
        const int j = idx / F_;
        const int e = idx - j * F_;
        Wl[j][e] = fcW[(size_t)(nc * 64 + j) * (H_ * F_) + h * F_ + e];
    }
    __syncthreads();

    for (int idx = t; idx < F_ * 64; idx += 256) {
        const int d = idx >> 6;
        const int j = idx & 63;
        float g = 0.f;
#pragma unroll 5
        for (int e = 0; e < F_; ++e) g = fmaf(S[d][e], Wl[j][e], g);
        const int n = nc * 64 + j;
        if (d == 0) gt0[((size_t)b * 512 + n) * 8 + h] = g;
        else        Gq[((size_t)b * 512 + n) * 512 + h * 64 + (d - 1)] = g;
    }
}

// ---------------- K4b: W2 = Gq @ Wq (packed bf16); P; C2 ----------------
__global__ __launch_bounds__(256)
void w2_build(const float* __restrict__ Gq, const float* __restrict__ gt0,
              const float* __restrict__ Wq, const float* __restrict__ bq,
              const float* __restrict__ fcb, ushort* __restrict__ W2pk,
              float* __restrict__ Pv, float* __restrict__ C2v)
{
    const int kt  = blockIdx.x;
    const int ntb = blockIdx.y;
    const int b   = blockIdx.z;
    const int t   = threadIdx.x;
    const int n0 = ntb * 64, k0 = kt * 64;

    __shared__ float Sg[64][65];
    __shared__ float Sw[64][65];

    const float* __restrict__ gq = Gq + (size_t)b * 262144;

    float acc[4][4];
#pragma unroll
    for (int i = 0; i < 4; ++i)
#pragma unroll
        for (int j = 0; j < 4; ++j) acc[i][j] = 0.f;
    float c2a[4] = {0.f, 0.f, 0.f, 0.f};

    const int tn = t >> 4, tk = t & 15;

    for (int dc = 0; dc < 8; ++dc) {
        const int d0 = dc * 64;
#pragma unroll
        for (int i = 0; i < 4; ++i) {
            const int idx4 = t + i * 256;        // 0..1023 float4 groups
            const int rr = idx4 >> 4;
            const int c4 = (idx4 & 15) * 4;
            const float4 gv = *(const float4*)&gq[(size_t)(n0 + rr) * 512 + d0 + c4];
            const float4 wv = *(const float4*)&Wq[(size_t)(d0 + rr) * 512 + k0 + c4];
            Sg[rr][c4] = gv.x; Sg[rr][c4 + 1] = gv.y;
            Sg[rr][c4 + 2] = gv.z; Sg[rr][c4 + 3] = gv.w;
            Sw[rr][c4] = wv.x; Sw[rr][c4 + 1] = wv.y;
            Sw[rr][c4 + 2] = wv.z; Sw[rr][c4 + 3] = wv.w;
        }
        __syncthreads();
        for (int dd = 0; dd < 64; ++dd) {
            float gf[4], wf[4];
#pragma unroll
            for (int i = 0; i < 4; ++i) gf[i] = Sg[tn * 4 + i][dd];
#pragma unroll
            for (int j = 0; j < 4; ++j) wf[j] = Sw[dd][tk * 4 + j];
#pragma unroll
            for (int i = 0; i < 4; ++i)
#pragma unroll
                for (int j = 0; j < 4; ++j)
                    acc[i][j] = fmaf(gf[i], wf[j], acc[i][j]);
        }
        if (tk == 0) {
            for (int dd = 0; dd < 64; ++dd) {
                const float bqv = bq[d0 + dd];
#pragma unroll
                for (int i = 0; i < 4; ++i)
                    c2a[i] = fmaf(bqv, Sg[tn * 4 + i][dd], c2a[i]);
            }
        }
        __syncthreads();
    }

    ushort* wp = W2pk + (size_t)b * 262144;
#pragma unroll
    for (int i = 0; i < 4; ++i)
#pragma unroll
        for (int j = 0; j < 4; ++j) {
            const int n = n0 + tn * 4 + i;
            const int k = k0 + tk * 4 + j;
            wp[(size_t)((n >> 7) * 16 + (k >> 5)) * 4096 +
               ((k >> 3) & 3) * 1024 + (n & 127) * 8 + (k & 7)] = f2b(acc[i][j]);
        }
    if (kt == 0 && tk == 0) {
#pragma unroll
        for (int i = 0; i < 4; ++i) {
            const int n = n0 + tn * 4 + i;
            float p = 0.f;
#pragma unroll
            for (int h = 0; h < 8; ++h) p += gt0[((size_t)b * 512 + n) * 8 + h];
            Pv[b * 512 + n]  = p;
            C2v[b * 512 + n] = fcb[n] + c2a[i];
        }
    }
}

// ---------------- K5: out = query @ W2 + pos*P + C2 ----------------
__global__ __launch_bounds__(512, 2)
void out_mfma(const float* __restrict__ query, const ushort* __restrict__ W2pk,
              const float* __restrict__ pos, const float* __restrict__ Pv,
              const float* __restrict__ C2v, float* __restrict__ out)
{
    const int x  = blockIdx.x;
    const int m0 = ((x & 7) * 32 + (x >> 3)) * 128;
    const int b  = m0 >> 13;
    const int t  = threadIdx.x;
    const int w  = t >> 6, l = t & 63;
    const int wm = (w >> 2) * 64, wn = (w & 3) * 128;
    const int lg = l >> 4, lm = l & 15;

    __shared__ __align__(16) float sAf[2][4096];
    __shared__ __align__(16) short sB[2][16384];

    f32x4 acc[4][8];
#pragma unroll
    for (int i = 0; i < 4; ++i)
#pragma unroll
        for (int j = 0; j < 8; ++j) acc[i][j] = (f32x4){0.f, 0.f, 0.f, 0.f};

    const int lr = l >> 3;
    const int hg = (l & 7) ^ lr;
    const float* ag[2]; int alo[2];
#pragma unroll
    for (int i = 0; i < 2; ++i) {
        const int row = w * 16 + i * 8 + lr;
        ag[i]  = &query[(size_t)(m0 + row) * D_ + hg * 4];
        alo[i] = (w * 2 + i) * 256;
    }

    const ushort* bsrc[4];
#pragma unroll
    for (int nt = 0; nt < 4; ++nt)
        bsrc[nt] = W2pk + (size_t)b * 262144 + (size_t)(nt * 16) * 4096 + t * 8;

    int a0o[4], a1o[4], bro[8];
#pragma unroll
    for (int i = 0; i < 4; ++i) {
        const int r = wm + i * 16 + lm;
        a0o[i] = r * 32 + (((lg * 2)     ^ (r & 7)) * 4);
        a1o[i] = r * 32 + (((lg * 2 + 1) ^ (r & 7)) * 4);
    }
#pragma unroll
    for (int i = 0; i < 8; ++i) {
        const int col = wn + i * 16 + lm;
        bro[i] = (col >> 7) * 4096 + lg * 1024 + (col & 127) * 8;
    }

    auto stage = [&](int ks, int buf) {
#pragma unroll
        for (int i = 0; i < 2; ++i) GLD16(ag[i] + ks * 32, &sAf[buf][alo[i]]);
#pragma unroll
        for (int nt = 0; nt < 4; ++nt)
            GLD16(bsrc[nt] + (size_t)ks * 4096, &sB[buf][nt * 4096 + t * 8]);
    };

    stage(0, 0);
    int cur = 0;
#pragma unroll
    for (int ks = 0; ks < 16; ++ks) {
        __syncthreads();
        if (ks < 15) stage(ks + 1, cur ^ 1);

        short8 af[4], bfv[8];
#pragma unroll
        for (int i = 0; i < 4; ++i) {
            const f32x4 A0 = *(const f32x4*)&sAf[cur][a0o[i]];
            const f32x4 A1 = *(const f32x4*)&sAf[cur][a1o[i]];
            uint u0, u1, u2, u3;
            asm("v_cvt_pk_bf16_f32 %0, %1, %2" : "=v"(u0) : "v"(A0[0]), "v"(A0[1]));
            asm("v_cvt_pk_bf16_f32 %0, %1, %2" : "=v"(u1) : "v"(A0[2]), "v"(A0[3]));
            asm("v_cvt_pk_bf16_f32 %0, %1, %2" : "=v"(u2) : "v"(A1[0]), "v"(A1[1]));
            asm("v_cvt_pk_bf16_f32 %0, %1, %2" : "=v"(u3) : "v"(A1[2]), "v"(A1[3]));
            union { uint4v u4; short8 s8; } cv;
            cv.u4 = (uint4v){u0, u1, u2, u3};
            af[i] = cv.s8;
        }
#pragma unroll
        for (int i = 0; i < 8; ++i) bfv[i] = *(const short8*)&sB[cur][bro[i]];
#pragma unroll
        for (int mt = 0; mt < 4; ++mt)
#pragma unroll
            for (int nt = 0; nt < 8; ++nt)
                acc[mt][nt] = __builtin_amdgcn_mfma_f32_16x16x32_bf16(
                    af[mt], bfv[nt], acc[mt][nt], 0, 0, 0);

        cur ^= 1;
    }

    float pv[8], c2[8];
#pragma unroll
    for (int nt = 0; nt < 8; ++nt) {
        const int n = wn + nt * 16 + lm;
        pv[nt] = Pv[b * 512 + n];
        c2[nt] = C2v[b * 512 + n];
    }

#pragma unroll
    for (int mt = 0; mt < 4; ++mt) {
#pragma unroll
        for (int r = 0; r < 4; ++r) {
            const int row = m0 + wm + mt * 16 + lg * 4 + r;
            const float pr = pos[row];
            float* orow = out + (size_t)row * D_;
#pragma unroll
            for (int nt = 0; nt < 8; ++nt)
                orow[wn + nt * 16 + lm] = acc[mt][nt][r] + pr * pv[nt] + c2[nt];
        }
    }
}

extern "C" void kernel_launch(void* const* d_in, const int* in_sizes, int n_in,
                              void* d_out, int out_size, void* d_ws, size_t ws_size,
                              hipStream_t stream)
{
    const float* query = (const float*)d_in[0];
    const float* key   = (const float*)d_in[1];
    const float* value = (const float*)d_in[2];
    const float* pos   = (const float*)d_in[3];
    const float* Wq    = (const float*)d_in[4];
    const float* bq    = (const float*)d_in[5];
    const float* Wk    = (const float*)d_in[6];
    const float* bk    = (const float*)d_in[7];
    const float* Wv    = (const float*)d_in[8];
    const float* bv    = (const float*)d_in[9];
    const float* gK    = (const float*)d_in[10];
    const float* betaK = (const float*)d_in[11];
    const float* gV    = (const float*)d_in[12];
    const float* betaV = (const float*)d_in[13];
    const float* fcW   = (const float*)d_in[14];
    const float* fcb   = (const float*)d_in[15];

    char* ws = (char*)d_ws;
    ushort* Kh       = (ushort*)(ws + 0);            // [4][8][8192][80] bf16
    ushort* Vh       = (ushort*)(ws + 41943040);     // [4][8][8192][80] bf16
    ushort* Wb       = (ushort*)(ws + 83886080);     // packed tiles (1 MB)
    float*  attn_acc = (float*) (ws + 84934656);     // [32][80*80] fp32
    float*  partial  = (float*) (ws + 85753856);     // [32][32][80*80] fp32 (26 MB)
    float*  Gq       = (float*) (ws + 112307456);    // [4][512][512] fp32 (wait-fixed below)
    float*  gt0      = (float*) (ws + 116501760);
    ushort* W2pk     = (ushort*)(ws + 116567296);    // 2 MB
    float*  Pv       = (float*) (ws + 118664448);
    float*  C2v      = (float*) (ws + 118672640);

    float* att_out  = (float*)d_out;                 // [4][8192][512]
    float* attn_out = att_out + 16777216;            // [4][8][65][65]

    cast_w<<<dim3(256), 256, 0, stream>>>(Wk, Wv, Wb);

    proj_mfma<<<dim3(256, 2), 512, 0, stream>>>(
        key, value, Wb, bk, bv, pos, gK, betaK, gV, betaV, Kh, Vh);

    attn_accum<<<dim3(8, 8, 4), 256, 0, stream>>>(Kh, Vh, partial);

    acc_reduce<<<dim3(4, 32), 256, 0, stream>>>(partial, attn_acc);

    attn_fin<<<dim3(8, 8, 4), 256, 0, stream>>>(attn_acc, fcW, attn_out, Gq, gt0);

    w2_build<<<dim3(8, 8, 4), 256, 0, stream>>>(Gq, gt0, Wq, bq, fcb, W2pk, Pv, C2v);

    out_mfma<<<dim3(256), 512, 0, stream>>>(query, W2pk, pos, Pv, C2v, att_out);
}